// Round 9
// baseline (399.082 us; speedup 1.0000x reference)
//
#include <hip/hip_runtime.h>

#define N 4096
#define CIN 64
#define NB 2
#define NBLK 512

typedef unsigned short u16;
typedef short bf16x8 __attribute__((ext_vector_type(8)));
typedef float f32x4 __attribute__((ext_vector_type(4)));

// workspace layout (float offsets). OFF_V region holds bf16 (u16) V.
#define OFF_QT 0
#define OFF_KT (OFF_QT + NB*N*8)
#define OFF_JT (OFF_KT + NB*N*8)
#define OFF_V  (OFF_JT + NB*N*8)
#define OFF_QK (OFF_V + NB*CIN*N)
#define OFF_MX (OFF_QK + NB*N*8)
#define OFF_SC (OFF_MX + NB*N)
#define OFF_CTR (OFF_SC + NB*N)   // [0..2]=arrive counters, [3]=generation flag

__device__ __forceinline__ u16 f2bf(float f) {
    union { float f; unsigned u; } v; v.f = f;
    unsigned r = (v.u + 0x7fffu + ((v.u >> 16) & 1u)) >> 16;  // RNE
    return (u16)r;
}

// Grid barrier, RMW-free polling: arrive = one atomicAdd per block; last
// arriver publishes generation flag; everyone else spins on an agent-scope
// atomic LOAD (no atomic-ALU serialization, unlike r8's atomicAdd(ctr,0)
// poll which cost ~65us/barrier). Spin bounded -> fail-fast, never hangs.
__device__ __forceinline__ void gridbar(unsigned* base, int barid) {
    __syncthreads();
    if (threadIdx.x == 0) {
        __threadfence();                        // release
        unsigned old = atomicAdd(&base[barid], 1u);
        unsigned* flag = base + 3;
        unsigned gen = (unsigned)(barid + 1);
        if (old == NBLK - 1) {
            __hip_atomic_store(flag, gen, __ATOMIC_RELEASE, __HIP_MEMORY_SCOPE_AGENT);
        } else {
            int guard = 0;
            while (__hip_atomic_load(flag, __ATOMIC_ACQUIRE, __HIP_MEMORY_SCOPE_AGENT) < gen
                   && guard < (1 << 22)) {
                __builtin_amdgcn_s_sleep(4);
                ++guard;
            }
        }
        __threadfence();                        // acquire
    }
    __syncthreads();
}

// Single fused kernel: prep -> kj/qkj -> row-stats -> MFMA pass2.
// 512 blocks x 256 thr; 2 blocks/CU co-resident.
__global__ __launch_bounds__(256, 2) void fused(
        const float* __restrict__ x,
        const float* __restrict__ wq, const float* __restrict__ bq,
        const float* __restrict__ wk, const float* __restrict__ bk,
        const float* __restrict__ wj, const float* __restrict__ bj,
        const float* __restrict__ wv, const float* __restrict__ bv,
        const float* __restrict__ gamma,
        float* __restrict__ ws, float* __restrict__ out) {
    const int t   = threadIdx.x;
    const int gid = blockIdx.x;
    u16* vbf = (u16*)(ws + OFF_V);
    unsigned* ctr = (unsigned*)(ws + OFF_CTR);

    __shared__ union {
        struct { u16 Pt[64][72]; u16 Vt[64][72]; float ks[64][8]; } p5;   // pass2
        struct { float kjpart[4][64]; float kjs[64]; } p3;                 // kj/qkj
    } sm;

    // ---------------- phase 1: prep q,k,j,v + out=x --------------------------
    {
        int bi = gid & 15, y = (gid >> 4) & 15, b = gid >> 8;
        int n = bi * 256 + t;
        const float* xb = x + (size_t)b * CIN * N + n;
        if (y < 8) {
            int cq = y;
            int d = n & 15, w = (n >> 4) & 15, h = n >> 8;
            int owl = (w > 0) ? -16 : 0,  owh = (w < 15) ? 16 : 0;
            int ohl = (h > 0) ? -256 : 0, ohh = (h < 15) ? 256 : 0;
            int odl = (d > 0) ? -1 : 0,   odh = (d < 15) ? 1 : 0;
            float mwl = (w > 0) ? 1.f : 0.f, mwh = (w < 15) ? 1.f : 0.f;
            float mhl = (h > 0) ? 1.f : 0.f, mhh = (h < 15) ? 1.f : 0.f;
            float mdl = (d > 0) ? 1.f : 0.f, mdh = (d < 15) ? 1.f : 0.f;
            float q = bq[cq], k = bk[cq], j = bj[cq];
            for (int c0 = 0; c0 < CIN; c0 += 8) {
                float xc[8], xwl[8], xwh[8], xhl[8], xhh[8], xdl[8], xdh[8];
#pragma unroll
                for (int u = 0; u < 8; ++u) {   // 56 independent loads in flight
                    const float* p = xb + (size_t)(c0 + u) * N;
                    xc[u]  = p[0];
                    xwl[u] = p[owl]; xwh[u] = p[owh];
                    xhl[u] = p[ohl]; xhh[u] = p[ohh];
                    xdl[u] = p[odl]; xdh[u] = p[odh];
                }
#pragma unroll
                for (int u = 0; u < 8; ++u) {
                    int c = c0 + u;
                    const float* wqr = wq + (cq * CIN + c) * 3;
                    const float* wkr = wk + (cq * CIN + c) * 3;
                    const float* wjr = wj + (cq * CIN + c) * 3;
                    q += wqr[0] * (xwl[u] * mwl) + wqr[1] * xc[u] + wqr[2] * (xwh[u] * mwh);
                    k += wkr[0] * (xhl[u] * mhl) + wkr[1] * xc[u] + wkr[2] * (xhh[u] * mhh);
                    j += wjr[0] * (xdl[u] * mdl) + wjr[1] * xc[u] + wjr[2] * (xdh[u] * mdh);
                }
            }
            size_t base = (size_t)(b * N + n) * 8 + cq;
            ws[OFF_QT + base] = q;
            ws[OFF_KT + base] = k;
            ws[OFF_JT + base] = j;
        } else {
            int yy = y - 8;
            int co0 = yy * 8;
            float acc[8];
#pragma unroll
            for (int i = 0; i < 8; ++i) acc[i] = bv[co0 + i];
            for (int c0 = 0; c0 < CIN; c0 += 8) {
                float xv[8];
#pragma unroll
                for (int u = 0; u < 8; ++u) xv[u] = xb[(size_t)(c0 + u) * N];
#pragma unroll
                for (int u = 0; u < 8; ++u)
#pragma unroll
                    for (int i = 0; i < 8; ++i)
                        acc[i] += wv[(co0 + i) * CIN + c0 + u] * xv[u];
                if ((c0 >> 3) == yy) {          // this block owns out-chunk yy
#pragma unroll
                    for (int u = 0; u < 8; ++u)
                        out[(size_t)(b * CIN + c0 + u) * N + n] = xv[u];
                }
            }
#pragma unroll
            for (int i = 0; i < 8; ++i)
                vbf[(size_t)(b * CIN + co0 + i) * N + n] = f2bf(acc[i]);
        }
    }
    gridbar(ctr, 0);

    // ---------------- phase 2: kj = K J^T (LDS), qkj[m] = q[m].kj (32 blocks)
    if (gid < 32) {
        const int lane = t & 63, wid = t >> 6;
        const int b = gid >> 4, mblk = gid & 15;
        const float* ktb = ws + OFF_KT + (size_t)b * N * 8;
        const float* jtb = ws + OFF_JT + (size_t)b * N * 8;
        const float* qtb = ws + OFF_QT + (size_t)b * N * 8;
        float acc[64];
#pragma unroll
        for (int i = 0; i < 64; ++i) acc[i] = 0.f;
        for (int i = 0; i < 16; ++i) {
            int nn = i * 256 + t;
            const float4* kt = (const float4*)(ktb + (size_t)nn * 8);
            const float4* jt = (const float4*)(jtb + (size_t)nn * 8);
            float4 ka = kt[0], kb = kt[1], ja = jt[0], jb = jt[1];
            float kv[8] = {ka.x, ka.y, ka.z, ka.w, kb.x, kb.y, kb.z, kb.w};
            float jv[8] = {ja.x, ja.y, ja.z, ja.w, jb.x, jb.y, jb.z, jb.w};
#pragma unroll
            for (int c = 0; c < 8; ++c)
#pragma unroll
                for (int dd = 0; dd < 8; ++dd) acc[c * 8 + dd] += kv[c] * jv[dd];
        }
#pragma unroll
        for (int s = 32; s >= 1; s >>= 1)
#pragma unroll
            for (int i = 0; i < 64; ++i) acc[i] += __shfl_down(acc[i], s, 64);
        if (lane == 0) {
#pragma unroll
            for (int i = 0; i < 64; ++i) sm.p3.kjpart[wid][i] = acc[i];
        }
        __syncthreads();
        if (t < 64) sm.p3.kjs[t] = sm.p3.kjpart[0][t] + sm.p3.kjpart[1][t]
                                 + sm.p3.kjpart[2][t] + sm.p3.kjpart[3][t];
        __syncthreads();
        float kjr[64];
#pragma unroll
        for (int i = 0; i < 64; ++i) kjr[i] = sm.p3.kjs[i];
        int m = mblk * 256 + t;
        const float4* qt = (const float4*)(qtb + (size_t)m * 8);
        float4 qa = qt[0], qb = qt[1];
        float qv[8] = {qa.x, qa.y, qa.z, qa.w, qb.x, qb.y, qb.z, qb.w};
        float o[8];
#pragma unroll
        for (int dd = 0; dd < 8; ++dd) {
            float a = 0.f;
#pragma unroll
            for (int c = 0; c < 8; ++c) a += qv[c] * kjr[c * 8 + dd];
            o[dd] = a;
        }
        float4* dst = (float4*)(ws + OFF_QK + (size_t)(b * N + m) * 8);
        dst[0] = make_float4(o[0], o[1], o[2], o[3]);
        dst[1] = make_float4(o[4], o[5], o[6], o[7]);
    }
    gridbar(ctr, 1);

    // ---------------- phase 3: row softmax stats (pass1) ---------------------
    {
        int wid = t >> 6, lane = t & 63;
        int r0 = (gid * 4 + wid) * 4;
        int b = r0 >> 12;
        float4 qa[4], qb[4];
#pragma unroll
        for (int rr = 0; rr < 4; ++rr) {
            const float4* q4 = (const float4*)(ws + OFF_QK + (size_t)(r0 + rr) * 8);
            qa[rr] = q4[0]; qb[rr] = q4[1];
        }
        const float* ktb = ws + OFF_KT + (size_t)b * N * 8;
        float mx[4], smv[4];
#pragma unroll
        for (int rr = 0; rr < 4; ++rr) { mx[rr] = -3.0e38f; smv[rr] = 0.f; }
#pragma unroll 4
        for (int i = 0; i < 64; ++i) {
            int m = i * 64 + lane;
            const float4* kk4 = (const float4*)(ktb + (size_t)m * 8);
            float4 ka = kk4[0], kb = kk4[1];
#pragma unroll
            for (int rr = 0; rr < 4; ++rr) {
                float a = qa[rr].x * ka.x + qa[rr].y * ka.y + qa[rr].z * ka.z + qa[rr].w * ka.w
                        + qb[rr].x * kb.x + qb[rr].y * kb.y + qb[rr].z * kb.z + qb[rr].w * kb.w;
                float nm = fmaxf(mx[rr], a);
                smv[rr] = smv[rr] * __expf(mx[rr] - nm) + __expf(a - nm);
                mx[rr] = nm;
            }
        }
#pragma unroll
        for (int s = 32; s >= 1; s >>= 1)
#pragma unroll
            for (int rr = 0; rr < 4; ++rr) {
                float omx = __shfl_xor(mx[rr], s, 64);
                float osm = __shfl_xor(smv[rr], s, 64);
                float nm = fmaxf(mx[rr], omx);
                smv[rr] = smv[rr] * __expf(mx[rr] - nm) + osm * __expf(omx - nm);
                mx[rr] = nm;
            }
        if (lane == 0) {
            float g = gamma[0];
#pragma unroll
            for (int rr = 0; rr < 4; ++rr) {
                ws[OFF_MX + r0 + rr] = mx[rr];
                ws[OFF_SC + r0 + rr] = g / smv[rr];
            }
        }
    }
    gridbar(ctr, 2);

    // ---------------- phase 4: pass2 MFMA (n-slice = 4) ----------------------
    {
        const int mt = gid & 63, ns = (gid >> 6) & 3, b = gid >> 8;
        const int m0 = mt * 64;
        const float* qkT = ws + OFF_QK + (size_t)b * N * 8;
        const float* ktb = ws + OFF_KT + (size_t)b * N * 8;
        const float* mxv = ws + OFF_MX + (size_t)b * N;
        const float* scv = ws + OFF_SC + (size_t)b * N;
        const u16*   vb  = vbf + (size_t)b * CIN * N;

        if (t < 128) ((float4*)sm.p5.ks)[t] = ((const float4*)(ktb + (size_t)m0 * 8))[t];

        const int lane = t & 63;
        const int wid  = t >> 6;
        const int l16  = lane & 15;
        const int lq   = lane >> 4;
        const int vc   = t >> 3;
        const int vseg = t & 7;

        f32x4 acc[4];
#pragma unroll
        for (int i = 0; i < 4; ++i) acc[i] = (f32x4){0.f, 0.f, 0.f, 0.f};

        for (int ch = 0; ch < 16; ++ch) {
            const int n0 = ns * 1024 + ch * 64;
            const int n  = n0 + lane;
            const float4* q4 = (const float4*)(qkT + (size_t)n * 8);
            float4 qa = q4[0], qb = q4[1];
            float mxl = mxv[n], sl = scv[n];
            uint4 v0 = *(const uint4*)(vb + (size_t)vc        * N + n0 + vseg * 8);
            uint4 v1 = *(const uint4*)(vb + (size_t)(vc + 32) * N + n0 + vseg * 8);
            __syncthreads();        // prev chunk's MFMA reads done (ch 0: ks staged)
#pragma unroll
            for (int r = 0; r < 16; ++r) {
                int mi = wid * 16 + r;
                float4 k0 = *(const float4*)&sm.p5.ks[mi][0];
                float4 k1 = *(const float4*)&sm.p5.ks[mi][4];
                float a = qa.x * k0.x + qa.y * k0.y + qa.z * k0.z + qa.w * k0.w
                        + qb.x * k1.x + qb.y * k1.y + qb.z * k1.z + qb.w * k1.w;
                sm.p5.Pt[mi][lane] = f2bf(__expf(a - mxl) * sl);
            }
            *(uint4*)&sm.p5.Vt[vc][vseg * 8]      = v0;
            *(uint4*)&sm.p5.Vt[vc + 32][vseg * 8] = v1;
            __syncthreads();
#pragma unroll
            for (int kk = 0; kk < 2; ++kk) {
                int k0i = kk * 32 + lq * 8;
                bf16x8 bfrag = *(const bf16x8*)&sm.p5.Pt[wid * 16 + l16][k0i];
#pragma unroll
                for (int ct = 0; ct < 4; ++ct) {
                    bf16x8 afrag = *(const bf16x8*)&sm.p5.Vt[ct * 16 + l16][k0i];
                    acc[ct] = __builtin_amdgcn_mfma_f32_16x16x32_bf16(afrag, bfrag, acc[ct], 0, 0, 0);
                }
            }
        }
        float* ob = out + (size_t)b * CIN * N;
        const int mcol = m0 + wid * 16 + l16;
#pragma unroll
        for (int ct = 0; ct < 4; ++ct)
#pragma unroll
            for (int r = 0; r < 4; ++r) {
                int c = ct * 16 + lq * 4 + r;
                atomicAdd(&ob[(size_t)c * N + mcol], acc[ct][r]);
            }
    }
}

extern "C" void kernel_launch(void* const* d_in, const int* in_sizes, int n_in,
                              void* d_out, int out_size, void* d_ws, size_t ws_size,
                              hipStream_t stream) {
    const float* x  = (const float*)d_in[0];
    const float* wq = (const float*)d_in[1];
    const float* bq = (const float*)d_in[2];
    const float* wk = (const float*)d_in[3];
    const float* bk = (const float*)d_in[4];
    const float* wj = (const float*)d_in[5];
    const float* bj = (const float*)d_in[6];
    const float* wv = (const float*)d_in[7];
    const float* bv = (const float*)d_in[8];
    const float* gamma = (const float*)d_in[9];
    float* ws  = (float*)d_ws;
    float* out = (float*)d_out;

    hipMemsetAsync(ws + OFF_CTR, 0, 16, stream);   // zero counters + flag
    fused<<<dim3(NBLK), dim3(256), 0, stream>>>(x, wq, bq, wk, bk, wj, bj,
                                                wv, bv, gamma, ws, out);
}

// Round 10
// 154.033 us; speedup vs baseline: 2.5909x; 2.5909x over previous
//
#include <hip/hip_runtime.h>

#define N 4096
#define CIN 64
#define NB 2

typedef unsigned short u16;
typedef short bf16x8 __attribute__((ext_vector_type(8)));
typedef float f32x4 __attribute__((ext_vector_type(4)));

// workspace layout (float offsets). OFF_V region holds bf16 (u16) V.
// OFF_QK holds qkj[n][8] = q[n] . kj
#define OFF_QT 0
#define OFF_KT (OFF_QT + NB*N*8)
#define OFF_JT (OFF_KT + NB*N*8)
#define OFF_V  (OFF_JT + NB*N*8)
#define OFF_QK (OFF_V + NB*CIN*N)
#define OFF_MX (OFF_QK + NB*N*8)
#define OFF_SC (OFF_MX + NB*N)

__device__ __forceinline__ u16 f2bf(float f) {
    union { float f; unsigned u; } v; v.f = f;
    unsigned r = (v.u + 0x7fffu + ((v.u >> 16) & 1u)) >> 16;  // RNE
    return (u16)r;
}

// ---- fused prep: y<8 -> q,k,j convs (cq=y); y>=8 -> v conv + out=x ----------
// grid (16, 16, 2) block 256 (512 blocks = 2/CU; the two halves co-schedule).
__global__ __launch_bounds__(256) void prep(
        const float* __restrict__ x,
        const float* __restrict__ wq, const float* __restrict__ bq,
        const float* __restrict__ wk, const float* __restrict__ bk,
        const float* __restrict__ wj, const float* __restrict__ bj,
        const float* __restrict__ wv, const float* __restrict__ bv,
        float* __restrict__ ws, u16* __restrict__ vbf, float* __restrict__ out) {
    int n = blockIdx.x * 256 + threadIdx.x;
    int y = blockIdx.y;
    int b = blockIdx.z;
    const float* xb = x + (size_t)b * CIN * N + n;

    if (y < 8) {
        int cq = y;
        int d = n & 15, w = (n >> 4) & 15, h = n >> 8;
        int owl = (w > 0) ? -16 : 0,  owh = (w < 15) ? 16 : 0;
        int ohl = (h > 0) ? -256 : 0, ohh = (h < 15) ? 256 : 0;
        int odl = (d > 0) ? -1 : 0,   odh = (d < 15) ? 1 : 0;
        float mwl = (w > 0) ? 1.f : 0.f, mwh = (w < 15) ? 1.f : 0.f;
        float mhl = (h > 0) ? 1.f : 0.f, mhh = (h < 15) ? 1.f : 0.f;
        float mdl = (d > 0) ? 1.f : 0.f, mdh = (d < 15) ? 1.f : 0.f;
        float q = bq[cq], k = bk[cq], j = bj[cq];
        for (int c0 = 0; c0 < CIN; c0 += 8) {
            float xc[8], xwl[8], xwh[8], xhl[8], xhh[8], xdl[8], xdh[8];
#pragma unroll
            for (int u = 0; u < 8; ++u) {       // 56 independent loads in flight
                const float* p = xb + (size_t)(c0 + u) * N;
                xc[u]  = p[0];
                xwl[u] = p[owl]; xwh[u] = p[owh];
                xhl[u] = p[ohl]; xhh[u] = p[ohh];
                xdl[u] = p[odl]; xdh[u] = p[odh];
            }
#pragma unroll
            for (int u = 0; u < 8; ++u) {
                int c = c0 + u;
                const float* wqr = wq + (cq * CIN + c) * 3;
                const float* wkr = wk + (cq * CIN + c) * 3;
                const float* wjr = wj + (cq * CIN + c) * 3;
                q += wqr[0] * (xwl[u] * mwl) + wqr[1] * xc[u] + wqr[2] * (xwh[u] * mwh);
                k += wkr[0] * (xhl[u] * mhl) + wkr[1] * xc[u] + wkr[2] * (xhh[u] * mhh);
                j += wjr[0] * (xdl[u] * mdl) + wjr[1] * xc[u] + wjr[2] * (xdh[u] * mdh);
            }
        }
        size_t base = (size_t)(b * N + n) * 8 + cq;
        ws[OFF_QT + base] = q;
        ws[OFF_KT + base] = k;
        ws[OFF_JT + base] = j;
    } else {
        int yy = y - 8;
        int co0 = yy * 8;
        float acc[8];
#pragma unroll
        for (int i = 0; i < 8; ++i) acc[i] = bv[co0 + i];
        for (int c0 = 0; c0 < CIN; c0 += 8) {
            float xv[8];
#pragma unroll
            for (int u = 0; u < 8; ++u) xv[u] = xb[(size_t)(c0 + u) * N];
#pragma unroll
            for (int u = 0; u < 8; ++u)
#pragma unroll
                for (int i = 0; i < 8; ++i)
                    acc[i] += wv[(co0 + i) * CIN + c0 + u] * xv[u];
            if ((c0 >> 3) == yy) {               // this block owns out-chunk yy
#pragma unroll
                for (int u = 0; u < 8; ++u)
                    out[(size_t)(b * CIN + c0 + u) * N + n] = xv[u];
            }
        }
#pragma unroll
        for (int i = 0; i < 8; ++i)
            vbf[(size_t)(b * CIN + co0 + i) * N + n] = f2bf(acc[i]);
    }
}

// ---- kjqkj: per-block recompute kj = K J^T (LDS), then qkj[m] = q[m].kj -----
// grid (16, 2) block 256. Self-contained (no memset needed).
__global__ __launch_bounds__(256) void kjqkj(const float* __restrict__ ws_in,
                                             float* __restrict__ ws) {
    __shared__ float kjpart[4][64];
    __shared__ float kjs[64];
    const int t = threadIdx.x, lane = t & 63, wid = t >> 6;
    const int b = blockIdx.y;
    const float* ktb = ws_in + OFF_KT + (size_t)b * N * 8;
    const float* jtb = ws_in + OFF_JT + (size_t)b * N * 8;
    const float* qtb = ws_in + OFF_QT + (size_t)b * N * 8;

    float acc[64];
#pragma unroll
    for (int i = 0; i < 64; ++i) acc[i] = 0.f;
    for (int i = 0; i < 16; ++i) {
        int nn = i * 256 + t;
        const float4* kt = (const float4*)(ktb + (size_t)nn * 8);
        const float4* jt = (const float4*)(jtb + (size_t)nn * 8);
        float4 ka = kt[0], kb = kt[1], ja = jt[0], jb = jt[1];
        float kv[8] = {ka.x, ka.y, ka.z, ka.w, kb.x, kb.y, kb.z, kb.w};
        float jv[8] = {ja.x, ja.y, ja.z, ja.w, jb.x, jb.y, jb.z, jb.w};
#pragma unroll
        for (int c = 0; c < 8; ++c)
#pragma unroll
            for (int dd = 0; dd < 8; ++dd) acc[c * 8 + dd] += kv[c] * jv[dd];
    }
#pragma unroll
    for (int s = 32; s >= 1; s >>= 1)
#pragma unroll
        for (int i = 0; i < 64; ++i) acc[i] += __shfl_down(acc[i], s, 64);
    if (lane == 0) {
#pragma unroll
        for (int i = 0; i < 64; ++i) kjpart[wid][i] = acc[i];
    }
    __syncthreads();
    if (t < 64) kjs[t] = kjpart[0][t] + kjpart[1][t] + kjpart[2][t] + kjpart[3][t];
    __syncthreads();

    float kjr[64];
#pragma unroll
    for (int i = 0; i < 64; ++i) kjr[i] = kjs[i];   // LDS broadcast reads
    int m = blockIdx.x * 256 + t;
    const float4* qt = (const float4*)(qtb + (size_t)m * 8);
    float4 qa = qt[0], qb = qt[1];
    float qv[8] = {qa.x, qa.y, qa.z, qa.w, qb.x, qb.y, qb.z, qb.w};
    float o[8];
#pragma unroll
    for (int dd = 0; dd < 8; ++dd) {
        float a = 0.f;
#pragma unroll
        for (int c = 0; c < 8; ++c) a += qv[c] * kjr[c * 8 + dd];
        o[dd] = a;
    }
    float4* dst = (float4*)(ws + OFF_QK + (size_t)(b * N + m) * 8);
    dst[0] = make_float4(o[0], o[1], o[2], o[3]);
    dst[1] = make_float4(o[4], o[5], o[6], o[7]);
}

// ---- pass1: row softmax stats; aff[n,m] = qkj[n] . k[m] ---------------------
// grid 512 block 256; wave handles 4 rows, lanes split m
__global__ __launch_bounds__(256) void pass1(const float* __restrict__ ws,
                                             float* __restrict__ mx_o, float* __restrict__ sc_o,
                                             const float* __restrict__ gamma) {
    int wid = threadIdx.x >> 6, lane = threadIdx.x & 63;
    int gw = blockIdx.x * 4 + wid;
    int r0 = gw * 4;
    int b = r0 >> 12;
    float4 qa[4], qb[4];
#pragma unroll
    for (int rr = 0; rr < 4; ++rr) {
        const float4* q4 = (const float4*)(ws + OFF_QK + (size_t)(r0 + rr) * 8);
        qa[rr] = q4[0]; qb[rr] = q4[1];
    }
    const float* ktb = ws + OFF_KT + (size_t)b * N * 8;
    float mx[4], sm[4];
#pragma unroll
    for (int rr = 0; rr < 4; ++rr) { mx[rr] = -3.0e38f; sm[rr] = 0.f; }
#pragma unroll 4
    for (int i = 0; i < 64; ++i) {
        int m = i * 64 + lane;
        const float4* kk4 = (const float4*)(ktb + (size_t)m * 8);
        float4 ka = kk4[0], kb = kk4[1];
#pragma unroll
        for (int rr = 0; rr < 4; ++rr) {
            float a = qa[rr].x * ka.x + qa[rr].y * ka.y + qa[rr].z * ka.z + qa[rr].w * ka.w
                    + qb[rr].x * kb.x + qb[rr].y * kb.y + qb[rr].z * kb.z + qb[rr].w * kb.w;
            float nm = fmaxf(mx[rr], a);
            sm[rr] = sm[rr] * __expf(mx[rr] - nm) + __expf(a - nm);
            mx[rr] = nm;
        }
    }
#pragma unroll
    for (int s = 32; s >= 1; s >>= 1)
#pragma unroll
        for (int rr = 0; rr < 4; ++rr) {
            float omx = __shfl_xor(mx[rr], s, 64);
            float osm = __shfl_xor(sm[rr], s, 64);
            float nm = fmaxf(mx[rr], omx);
            sm[rr] = sm[rr] * __expf(mx[rr] - nm) + osm * __expf(omx - nm);
            mx[rr] = nm;
        }
    if (lane == 0) {
        float g = gamma[0];
#pragma unroll
        for (int rr = 0; rr < 4; ++rr) {
            mx_o[r0 + rr] = mx[rr];
            sc_o[r0 + rr] = g / sm[rr];
        }
    }
}

// ---- pass2: out += V_bf16 . (sc*exp(qkj[n].k[m]-mx))_bf16 via MFMA ----------
// grid (64, 8, 2) block 256: x = m-tile(64), y = n-slice(512), z = b
__global__ __launch_bounds__(256) void pass2(const float* __restrict__ ws,
                                             const u16* __restrict__ vbf,
                                             float* __restrict__ out) {
    __shared__ u16 Pt[64][72];      // P' tile: [m][n]  (B-frag: B[k=n][col=m])
    __shared__ u16 Vt[64][72];      // V tile:  [c][n]  (A-frag: A[row=c][k=n])
    __shared__ float ks[64][8];     // k for this m-tile
    const int t  = threadIdx.x;
    const int b  = blockIdx.z;
    const int m0 = blockIdx.x * 64;
    const int ns = blockIdx.y;
    const float* qkT = ws + OFF_QK + (size_t)b * N * 8;
    const float* ktb = ws + OFF_KT + (size_t)b * N * 8;
    const float* mxv = ws + OFF_MX + (size_t)b * N;
    const float* scv = ws + OFF_SC + (size_t)b * N;
    const u16*   vb  = vbf + (size_t)b * CIN * N;

    if (t < 128) ((float4*)ks)[t] = ((const float4*)(ktb + (size_t)m0 * 8))[t];

    const int lane = t & 63;
    const int wid  = t >> 6;        // wave id -> m-subtile
    const int l16  = lane & 15;
    const int lq   = lane >> 4;     // lane quad -> k-octet / acc row group
    const int vc   = t >> 3;        // V staging row 0..31
    const int vseg = t & 7;

    f32x4 acc[4];
#pragma unroll
    for (int i = 0; i < 4; ++i) acc[i] = (f32x4){0.f, 0.f, 0.f, 0.f};

    for (int ch = 0; ch < 8; ++ch) {
        const int n0 = ns * 512 + ch * 64;
        const int n  = n0 + lane;
        const float4* q4 = (const float4*)(qkT + (size_t)n * 8);
        float4 qa = q4[0], qb = q4[1];
        float mxl = mxv[n], sl = scv[n];
        uint4 v0 = *(const uint4*)(vb + (size_t)vc        * N + n0 + vseg * 8);
        uint4 v1 = *(const uint4*)(vb + (size_t)(vc + 32) * N + n0 + vseg * 8);
        __syncthreads();            // prev chunk's MFMA reads done (chunk 0: ks staged)
#pragma unroll
        for (int r = 0; r < 16; ++r) {
            int mi = wid * 16 + r;
            float4 k0 = *(const float4*)&ks[mi][0];
            float4 k1 = *(const float4*)&ks[mi][4];
            float a = qa.x * k0.x + qa.y * k0.y + qa.z * k0.z + qa.w * k0.w
                    + qb.x * k1.x + qb.y * k1.y + qb.z * k1.z + qb.w * k1.w;
            Pt[mi][lane] = f2bf(__expf(a - mxl) * sl);  // gamma/rowsum folded in
        }
        *(uint4*)&Vt[vc][vseg * 8]      = v0;
        *(uint4*)&Vt[vc + 32][vseg * 8] = v1;
        __syncthreads();
#pragma unroll
        for (int kk = 0; kk < 2; ++kk) {
            int k0i = kk * 32 + lq * 8;
            bf16x8 bfrag = *(const bf16x8*)&Pt[wid * 16 + l16][k0i];
#pragma unroll
            for (int ct = 0; ct < 4; ++ct) {
                bf16x8 afrag = *(const bf16x8*)&Vt[ct * 16 + l16][k0i];
                acc[ct] = __builtin_amdgcn_mfma_f32_16x16x32_bf16(afrag, bfrag, acc[ct], 0, 0, 0);
            }
        }
    }
    float* ob = out + (size_t)b * CIN * N;
    const int mcol = m0 + wid * 16 + l16;
#pragma unroll
    for (int ct = 0; ct < 4; ++ct)
#pragma unroll
        for (int r = 0; r < 4; ++r) {
            int c = ct * 16 + lq * 4 + r;
            atomicAdd(&ob[(size_t)c * N + mcol], acc[ct][r]);
        }
}

extern "C" void kernel_launch(void* const* d_in, const int* in_sizes, int n_in,
                              void* d_out, int out_size, void* d_ws, size_t ws_size,
                              hipStream_t stream) {
    const float* x  = (const float*)d_in[0];
    const float* wq = (const float*)d_in[1];
    const float* bq = (const float*)d_in[2];
    const float* wk = (const float*)d_in[3];
    const float* bk = (const float*)d_in[4];
    const float* wj = (const float*)d_in[5];
    const float* bj = (const float*)d_in[6];
    const float* wv = (const float*)d_in[7];
    const float* bv = (const float*)d_in[8];
    const float* gamma = (const float*)d_in[9];
    float* ws  = (float*)d_ws;
    float* out = (float*)d_out;
    u16* vbf = (u16*)(ws + OFF_V);

    prep<<<dim3(16, 16, 2), 256, 0, stream>>>(x, wq, bq, wk, bk, wj, bj, wv, bv, ws, vbf, out);
    kjqkj<<<dim3(16, 2), 256, 0, stream>>>(ws, ws);
    pass1<<<512, 256, 0, stream>>>(ws, ws + OFF_MX, ws + OFF_SC, gamma);
    pass2<<<dim3(64, 8, 2), 256, 0, stream>>>(ws, vbf, out);
}